// Round 8
// baseline (531.266 us; speedup 1.0000x reference)
//
#include <hip/hip_runtime.h>

#define NN 100000
#define NE 1600000
#define NBUCK 1563     // ceil(NN/64)
#define NBH 128        // histogram/placement blocks
#define CHUNK 12500    // NE/NBH
#define NBXB 12500     // NN*32/256 blocks for x->bf16

// ws layout (bytes), 16-aligned:
//   xb:    0           (25,600,000)  bf16 x
//   ghist: 25,600,000  (800,256)     [block i][bucket k]
//   boffT: 26,400,256  (800,256)     [bucket k][block i]
//   tot:   27,200,512  (6,252)
//   bbase: 27,206,768  (6,252)
//   row_start: 27,213,024 ((NN+1)*4)
//   dinv:  27,613,040  (400,000)
//   ebuf:  28,013,056  (6,400,000)   bucket-sorted packed {src | dstlo<<17}
//   csr:   34,413,056  (6,400,000)   node-sorted src-only
//   T2:    40,813,056  (12,800,000)  dense t2 bf16 [NN][64]
// total ~53.6 MB.

typedef short bf16x8 __attribute__((ext_vector_type(8)));
typedef float f32x4  __attribute__((ext_vector_type(4)));

__device__ __forceinline__ float b2f(unsigned short u) {
    return __uint_as_float(((unsigned int)u) << 16);
}
__device__ __forceinline__ unsigned short f2b(float f) {
    unsigned int x = __float_as_uint(f);
    x += 0x7FFFu + ((x >> 16) & 1u);   // RNE
    return (unsigned short)(x >> 16);
}

// ---- fused: x->bf16 (blocks [0,NBXB)) + bucket histogram ----
__global__ __launch_bounds__(256) void k_pre(const float* __restrict__ x,
                                             unsigned short* __restrict__ xb,
                                             const int* __restrict__ dst,
                                             int* __restrict__ ghist) {
    int b = blockIdx.x;
    if (b < NBXB) {
        int id = b * 256 + threadIdx.x;
        float4 v = ((const float4*)x)[id];
        ushort4 o;
        o.x = f2b(v.x); o.y = f2b(v.y); o.z = f2b(v.z); o.w = f2b(v.w);
        ((ushort4*)xb)[id] = o;
        return;
    }
    __shared__ int h[NBUCK];
    int tid = threadIdx.x;
    int i = b - NBXB;
    for (int k = tid; k < NBUCK; k += 256) h[k] = 0;
    __syncthreads();
    int e0 = i * CHUNK;
    for (int e = e0 + tid; e < e0 + CHUNK; e += 256) {
        unsigned d = (unsigned)dst[e];
        if (d < NN) atomicAdd(&h[d >> 6], 1);
    }
    __syncthreads();
    for (int k = tid; k < NBUCK; k += 256) ghist[i * NBUCK + k] = h[k];
}

// ---- fused scans (one block): boffT, tot, bbase ----
__global__ __launch_bounds__(256) void k_scan(const int* __restrict__ ghist,
                                              int* __restrict__ boffT,
                                              int* __restrict__ tot,
                                              int* __restrict__ bbase) {
    __shared__ int tot_s[NBUCK];
    __shared__ int s[256];
    int tid = threadIdx.x;
    for (int k = tid; k < NBUCK; k += 256) {
        int sum = 0;
        for (int i = 0; i < NBH; ++i) {
            int c = ghist[i * NBUCK + k];
            boffT[k * NBH + i] = sum;
            sum += c;
        }
        tot[k] = sum; tot_s[k] = sum;
    }
    __syncthreads();
    int k0 = tid * 7;
    int v[7]; int S = 0;
#pragma unroll
    for (int q = 0; q < 7; ++q) {
        int k = k0 + q;
        v[q] = (k < NBUCK) ? tot_s[k] : 0;
        S += v[q];
    }
    s[tid] = S;
    __syncthreads();
    for (int off = 1; off < 256; off <<= 1) {
        int t = (tid >= off) ? s[tid - off] : 0;
        __syncthreads();
        s[tid] += t;
        __syncthreads();
    }
    int run = s[tid] - S;
#pragma unroll
    for (int q = 0; q < 7; ++q) {
        int k = k0 + q;
        if (k < NBUCK) { bbase[k] = run; run += v[q]; }
    }
}

// ---- placement: bucket-sorted packed records via LDS cursors ----
__global__ __launch_bounds__(256) void k_place(const int* __restrict__ src,
                                               const int* __restrict__ dst,
                                               const int* __restrict__ bbase,
                                               const int* __restrict__ boffT,
                                               int* __restrict__ ebuf) {
    __shared__ int cur[NBUCK];
    int tid = threadIdx.x, i = blockIdx.x;
    for (int k = tid; k < NBUCK; k += 256) cur[k] = bbase[k] + boffT[k * NBH + i];
    __syncthreads();
    int e0 = i * CHUNK;
    for (int e = e0 + tid; e < e0 + CHUNK; e += 256) {
        unsigned d = (unsigned)dst[e];
        if (d >= NN) continue;
        unsigned s = (unsigned)src[e];
        if (s >= NN) s = 0;
        int pos = atomicAdd(&cur[d >> 6], 1);
        ebuf[pos] = (int)(s | ((d & 63u) << 17));
    }
}

// ---- per-bucket: per-node counts -> row_start/dinv, src-only csr ----
__global__ __launch_bounds__(256) void k_binC(const int* __restrict__ bbase,
                                              const int* __restrict__ tot,
                                              const int* __restrict__ ebuf,
                                              int* __restrict__ row_start,
                                              float* __restrict__ dinv,
                                              int* __restrict__ csr) {
    __shared__ int cnt[64], excl[64], cur[64];
    int b = blockIdx.x, tid = threadIdx.x;
    int n0 = b * 64;
    int base = bbase[b], end = base + tot[b];
    if (tid < 64) cnt[tid] = 0;
    __syncthreads();
    for (int i = base + tid; i < end; i += 256)
        atomicAdd(&cnt[((unsigned)ebuf[i]) >> 17], 1);
    __syncthreads();
    if (tid == 0) {
        int run = 0;
        for (int t = 0; t < 64; ++t) { excl[t] = run; run += cnt[t]; }
    }
    __syncthreads();
    if (tid < 64) {
        int node = n0 + tid;
        if (node < NN) {
            row_start[node] = base + excl[tid];
            dinv[node] = rsqrtf((float)cnt[tid] + 1.0f);
        }
        cur[tid] = base + excl[tid];
    }
    if (b == NBUCK - 1 && tid == 0) row_start[NN] = end;
    __syncthreads();
    for (int i = base + tid; i < end; i += 256) {
        unsigned rec = (unsigned)ebuf[i];
        int pos = atomicAdd(&cur[rec >> 17], 1);
        csr[pos] = (int)(rec & 0x1FFFFu);
    }
}

// ---- fused layer-1 aggregate + GEMM1 + GEMM2: T2 = bf16(relu(agg@W1+b1)@W2) ----
// 64 nodes/block, 4 waves x 16 nodes; agg results stay in LDS as A-operands.
__global__ __launch_bounds__(256) void k_agg1g(const unsigned short* __restrict__ xb,
                                               const float* __restrict__ dinv,
                                               const int* __restrict__ row_start,
                                               const int* __restrict__ csr,
                                               const float* __restrict__ W1,
                                               const float* __restrict__ b1,
                                               const float* __restrict__ W2,
                                               unsigned short* __restrict__ T2) {
    __shared__ short AgCl[4][16][128];   // 16 KB: agg rows, then h2 C-tile (per-wave slice)
    __shared__ short Wl1[16384];         // 32 KB: [ct8][ks4][lane64][j8]; first 8 KB reused as Ct[64][64]
    __shared__ short Wl2[8192];          // 16 KB: [ct4][ks4][lane64][j8]
    const int tid = threadIdx.x;
    const int w = tid >> 6, lane = tid & 63;
    const int n0 = blockIdx.x * 64;

    // stage weights (bf16, swizzled for ds_read_b128 B-frags)
    for (int i = tid; i < 16384; i += 256) {
        int j = i & 7, l = (i >> 3) & 63, ks = (i >> 9) & 3, ct = i >> 11;
        Wl1[i] = (short)f2b(W1[(ks * 32 + ((l >> 4) << 3) + j) * 128 + ct * 16 + (l & 15)]);
    }
    for (int i = tid; i < 8192; i += 256) {
        int j = i & 7, l = (i >> 3) & 63, ks = (i >> 9) & 3, ct = i >> 11;
        Wl2[i] = (short)f2b(W2[(ks * 32 + ((l >> 4) << 3) + j) * 64 + ct * 16 + (l & 15)]);
    }

    // gather phase: wave w aggregates nodes n0 + w*16 + t, t = 0..15
    for (int t = 0; t < 16; ++t) {
        int node = n0 + w * 16 + t;
        float ax = 0.f, ay = 0.f;
        if (node < NN) {
            float dv = dinv[node]; float sn = dv * dv;
            unsigned int sv = ((const unsigned int*)(xb + (size_t)node * 128))[lane];
            ax = b2f((unsigned short)(sv & 0xFFFF)) * sn;
            ay = b2f((unsigned short)(sv >> 16)) * sn;
            int base = row_start[node], end = row_start[node + 1];
            for (int i0 = base; i0 < end; i0 += 64) {
                int idx = i0 + lane;
                int s = (idx < end) ? csr[idx] : 0;
                float wv = (idx < end) ? dinv[s] * dv : 0.f;
                int m = min(64, end - i0);
                int j = 0;
                for (; j + 3 < m; j += 4) {
                    int   s0 = __shfl(s, j),     s1 = __shfl(s, j + 1);
                    int   s2 = __shfl(s, j + 2), s3 = __shfl(s, j + 3);
                    float w0 = __shfl(wv, j),     w1 = __shfl(wv, j + 1);
                    float w2 = __shfl(wv, j + 2), w3 = __shfl(wv, j + 3);
                    unsigned int v0 = ((const unsigned int*)(xb + (size_t)s0 * 128))[lane];
                    unsigned int v1 = ((const unsigned int*)(xb + (size_t)s1 * 128))[lane];
                    unsigned int v2 = ((const unsigned int*)(xb + (size_t)s2 * 128))[lane];
                    unsigned int v3 = ((const unsigned int*)(xb + (size_t)s3 * 128))[lane];
                    ax = fmaf(b2f((unsigned short)(v0 & 0xFFFF)), w0, ax);
                    ay = fmaf(b2f((unsigned short)(v0 >> 16)),    w0, ay);
                    ax = fmaf(b2f((unsigned short)(v1 & 0xFFFF)), w1, ax);
                    ay = fmaf(b2f((unsigned short)(v1 >> 16)),    w1, ay);
                    ax = fmaf(b2f((unsigned short)(v2 & 0xFFFF)), w2, ax);
                    ay = fmaf(b2f((unsigned short)(v2 >> 16)),    w2, ay);
                    ax = fmaf(b2f((unsigned short)(v3 & 0xFFFF)), w3, ax);
                    ay = fmaf(b2f((unsigned short)(v3 >> 16)),    w3, ay);
                }
                for (; j < m; ++j) {
                    int s0 = __shfl(s, j);
                    float w0 = __shfl(wv, j);
                    unsigned int v0 = ((const unsigned int*)(xb + (size_t)s0 * 128))[lane];
                    ax = fmaf(b2f((unsigned short)(v0 & 0xFFFF)), w0, ax);
                    ay = fmaf(b2f((unsigned short)(v0 >> 16)),    w0, ay);
                }
            }
        }
        ((unsigned int*)&AgCl[w][t][0])[lane] =
            (unsigned int)f2b(ax) | ((unsigned int)f2b(ay) << 16);
    }
    __syncthreads();   // weights staged + (own-wave) agg rows visible

    const int m16 = lane & 15, quad = lane >> 4;
    bf16x8 a[4];
#pragma unroll
    for (int ks = 0; ks < 4; ++ks)
        a[ks] = *(const bf16x8*)&AgCl[w][m16][ks * 32 + quad * 8];
    // layer 1: 8 col-tiles; C-write into own AgCl slice (own-wave data only)
#pragma unroll
    for (int ct = 0; ct < 8; ++ct) {
        f32x4 c = {0.f, 0.f, 0.f, 0.f};
#pragma unroll
        for (int ks = 0; ks < 4; ++ks) {
            bf16x8 b = *(const bf16x8*)&Wl1[((ct * 4 + ks) * 64 + lane) * 8];
            c = __builtin_amdgcn_mfma_f32_16x16x32_bf16(a[ks], b, c, 0, 0, 0);
        }
        int col = ct * 16 + m16;
        float bias = b1[col];
#pragma unroll
        for (int r = 0; r < 4; ++r)
            AgCl[w][quad * 4 + r][col] = (short)f2b(fmaxf(c[r] + bias, 0.f));
    }
    // h2 C-layout -> A-layout (own-wave slice)
    bf16x8 a2[4];
#pragma unroll
    for (int ks = 0; ks < 4; ++ks)
        a2[ks] = *(const bf16x8*)&AgCl[w][m16][ks * 32 + quad * 8];
    __syncthreads();   // all Wl1 reads done before Ct overwrite
    short* Ct = &Wl1[0];   // [64 rows][64 cols] = 8 KB
#pragma unroll
    for (int ct = 0; ct < 4; ++ct) {
        f32x4 c = {0.f, 0.f, 0.f, 0.f};
#pragma unroll
        for (int ks = 0; ks < 4; ++ks) {
            bf16x8 b = *(const bf16x8*)&Wl2[((ct * 4 + ks) * 64 + lane) * 8];
            c = __builtin_amdgcn_mfma_f32_16x16x32_bf16(a2[ks], b, c, 0, 0, 0);
        }
        int col = ct * 16 + m16;
#pragma unroll
        for (int r = 0; r < 4; ++r)
            Ct[(w * 16 + quad * 4 + r) * 64 + col] = (short)f2b(c[r]);
    }
    // store t2 rows (own-wave rows): 2 rows per iter, 32 lanes each
    for (int it = 0; it < 8; ++it) {
        int row = it * 2 + (lane >> 5), u = lane & 31;
        int node = n0 + w * 16 + row;
        if (node < NN)
            *(unsigned int*)((char*)T2 + (size_t)node * 128 + u * 4) =
                ((const unsigned int*)&Ct[(w * 16 + row) * 64])[u];
    }
}

// ---- layer-2 aggregate + epilogue, 2 nodes/wave (dword gathers) ----
__global__ __launch_bounds__(256) void k_agg2(const float* __restrict__ dinv,
                                              const int* __restrict__ row_start,
                                              const int* __restrict__ csr,
                                              const unsigned short* __restrict__ T2,
                                              const float* __restrict__ b2,
                                              float* __restrict__ outp) {
    int lane = threadIdx.x & 63;
    int half = lane >> 5, h = lane & 31;
    int node = blockIdx.x * 8 + (threadIdx.x >> 6) * 2 + half;   // grid = NN/8 exactly
    float dv = dinv[node]; float sn = dv * dv;
    unsigned int tv = *(const unsigned int*)((const char*)T2 + (size_t)node * 128 + h * 4);
    float ax = b2f((unsigned short)(tv & 0xFFFF)) * sn;
    float ay = b2f((unsigned short)(tv >> 16)) * sn;
    int base = row_start[node], end = row_start[node + 1];
    int m_own = end - base;
    int mmax = max(m_own, __shfl(m_own, lane ^ 32));
    int hsel = lane & 32;
    for (int off = 0; off < mmax; off += 32) {
        int idx = base + off + h;
        bool valid = (off + h) < m_own;
        int s = valid ? csr[idx] : 0;
        float wv = valid ? dinv[s] * dv : 0.f;
        int cnt = min(32, mmax - off);
        int j = 0;
        for (; j + 3 < cnt; j += 4) {
            int   s0 = __shfl(s, hsel + j),     s1 = __shfl(s, hsel + j + 1);
            int   s2 = __shfl(s, hsel + j + 2), s3 = __shfl(s, hsel + j + 3);
            float w0 = __shfl(wv, hsel + j),     w1 = __shfl(wv, hsel + j + 1);
            float w2 = __shfl(wv, hsel + j + 2), w3 = __shfl(wv, hsel + j + 3);
            unsigned int v0 = *(const unsigned int*)((const char*)T2 + (size_t)s0 * 128 + h * 4);
            unsigned int v1 = *(const unsigned int*)((const char*)T2 + (size_t)s1 * 128 + h * 4);
            unsigned int v2 = *(const unsigned int*)((const char*)T2 + (size_t)s2 * 128 + h * 4);
            unsigned int v3 = *(const unsigned int*)((const char*)T2 + (size_t)s3 * 128 + h * 4);
            ax = fmaf(b2f((unsigned short)(v0 & 0xFFFF)), w0, ax);
            ay = fmaf(b2f((unsigned short)(v0 >> 16)),    w0, ay);
            ax = fmaf(b2f((unsigned short)(v1 & 0xFFFF)), w1, ax);
            ay = fmaf(b2f((unsigned short)(v1 >> 16)),    w1, ay);
            ax = fmaf(b2f((unsigned short)(v2 & 0xFFFF)), w2, ax);
            ay = fmaf(b2f((unsigned short)(v2 >> 16)),    w2, ay);
            ax = fmaf(b2f((unsigned short)(v3 & 0xFFFF)), w3, ax);
            ay = fmaf(b2f((unsigned short)(v3 >> 16)),    w3, ay);
        }
        for (; j < cnt; ++j) {
            int s0 = __shfl(s, hsel + j);
            float w0 = __shfl(wv, hsel + j);
            unsigned int v0 = *(const unsigned int*)((const char*)T2 + (size_t)s0 * 128 + h * 4);
            ax = fmaf(b2f((unsigned short)(v0 & 0xFFFF)), w0, ax);
            ay = fmaf(b2f((unsigned short)(v0 >> 16)),    w0, ay);
        }
    }
    float2 bb = ((const float2*)b2)[h];
    float2 o; o.x = ax + bb.x; o.y = ay + bb.y;
    ((float2*)(outp + (size_t)node * 64))[h] = o;
}

extern "C" void kernel_launch(void* const* d_in, const int* in_sizes, int n_in,
                              void* d_out, int out_size, void* d_ws, size_t ws_size,
                              hipStream_t stream) {
    const float* x  = (const float*)d_in[0];
    const int*   ei = (const int*)d_in[1];
    const float* W1 = (const float*)d_in[2];
    const float* b1 = (const float*)d_in[3];
    const float* W2 = (const float*)d_in[4];
    const float* b2 = (const float*)d_in[5];
    float* out = (float*)d_out;
    const int* src = ei;
    const int* dst = ei + NE;

    char* ws = (char*)d_ws;
    unsigned short* xb        = (unsigned short*)(ws + 0);
    int*            ghist     = (int*)(ws + 25600000);
    int*            boffT     = (int*)(ws + 26400256);
    int*            tot       = (int*)(ws + 27200512);
    int*            bbase     = (int*)(ws + 27206768);
    int*            row_start = (int*)(ws + 27213024);
    float*          dinv      = (float*)(ws + 27613040);
    int*            ebuf      = (int*)(ws + 28013056);
    int*            csr       = (int*)(ws + 34413056);
    unsigned short* T2        = (unsigned short*)(ws + 40813056);

    k_pre  <<<NBXB + NBH, 256, 0, stream>>>(x, xb, dst, ghist);
    k_scan <<<1, 256, 0, stream>>>(ghist, boffT, tot, bbase);
    k_place<<<NBH, 256, 0, stream>>>(src, dst, bbase, boffT, ebuf);
    k_binC <<<NBUCK, 256, 0, stream>>>(bbase, tot, ebuf, row_start, dinv, csr);

    k_agg1g<<<NBUCK, 256, 0, stream>>>(xb, dinv, row_start, csr, W1, b1, W2, T2);
    k_agg2 <<<NN / 8, 256, 0, stream>>>(dinv, row_start, csr, T2, b2, out);
}

// Round 9
// 384.819 us; speedup vs baseline: 1.3806x; 1.3806x over previous
//
#include <hip/hip_runtime.h>

#define NN 100000
#define NE 1600000
#define NBUCK 1563     // ceil(NN/64)
#define NBH 1000       // histogram/placement blocks
#define CHUNK 1600     // NE/NBH
#define NBXB 12500     // NN*32/256 blocks for x->bf16

// ws layout (bytes), all offsets 8-aligned:
//   xb:        0           (25,600,000)  bf16 x
//   ghist:     25,600,000  (6,252,000)   [chunk i][bucket k]
//   boff:      32,000,000  (6,252,000)   [chunk i][bucket k] excl-scan within column
//   tot:       38,400,000  (6,252)
//   bbase:     38,440,000  (6,252)
//   row_start: 38,480,000  ((NN+1)*4)
//   dinv:      38,900,000  (400,000)
//   ebuf:      39,300,000  (6,400,000)   bucket-sorted packed {src | dstlo<<17}
//   csr:       45,700,000  (6,400,000)   node-sorted src-only
//   P:         52,100,000  (25,600,000)  256B/node: agg bf16 -> t2 bf16 in [0,128)
// total ~77.7 MB.

typedef short bf16x8 __attribute__((ext_vector_type(8)));
typedef float f32x4  __attribute__((ext_vector_type(4)));

__device__ __forceinline__ float b2f(unsigned short u) {
    return __uint_as_float(((unsigned int)u) << 16);
}
__device__ __forceinline__ unsigned short f2b(float f) {
    unsigned int x = __float_as_uint(f);
    x += 0x7FFFu + ((x >> 16) & 1u);   // RNE
    return (unsigned short)(x >> 16);
}

// ---- fused: bucket histogram (blocks [0,NBH)) + x->bf16 (rest) ----
// hist blocks first so they start immediately and overlap the xb stream.
__global__ __launch_bounds__(256) void k_pre(const float* __restrict__ x,
                                             unsigned short* __restrict__ xb,
                                             const int* __restrict__ dst,
                                             int* __restrict__ ghist) {
    int b = blockIdx.x;
    if (b >= NBH) {
        int id = (b - NBH) * 256 + threadIdx.x;
        float4 v = ((const float4*)x)[id];
        ushort4 o;
        o.x = f2b(v.x); o.y = f2b(v.y); o.z = f2b(v.z); o.w = f2b(v.w);
        ((ushort4*)xb)[id] = o;
        return;
    }
    __shared__ int h[NBUCK];
    int tid = threadIdx.x;
    for (int k = tid; k < NBUCK; k += 256) h[k] = 0;
    __syncthreads();
    int e0 = b * CHUNK;
    for (int e = e0 + tid; e < e0 + CHUNK; e += 256) {
        unsigned d = (unsigned)dst[e];
        if (d < NN) atomicAdd(&h[d >> 6], 1);
    }
    __syncthreads();
    for (int k = tid; k < NBUCK; k += 256) ghist[b * NBUCK + k] = h[k];
}

// ---- per-bucket scan over chunks (thread = bucket): boff[i][k], tot[k] ----
__global__ __launch_bounds__(256) void k_scanB(const int* __restrict__ ghist,
                                               int* __restrict__ boff,
                                               int* __restrict__ tot) {
    int k = blockIdx.x * 256 + threadIdx.x;
    if (k >= NBUCK) return;
    int sum = 0;
#pragma unroll 8
    for (int i = 0; i < NBH; ++i) {
        int c = ghist[i * NBUCK + k];
        boff[i * NBUCK + k] = sum;
        sum += c;
    }
    tot[k] = sum;
}

// ---- exclusive scan of bucket totals -> bbase (one block) ----
__global__ __launch_bounds__(256) void k_scanT(const int* __restrict__ tot,
                                               int* __restrict__ bbase) {
    __shared__ int s[256];
    int tid = threadIdx.x;
    int k0 = tid * 7;
    int v[7]; int S = 0;
#pragma unroll
    for (int q = 0; q < 7; ++q) {
        int k = k0 + q;
        v[q] = (k < NBUCK) ? tot[k] : 0;
        S += v[q];
    }
    s[tid] = S;
    __syncthreads();
    for (int off = 1; off < 256; off <<= 1) {
        int t = (tid >= off) ? s[tid - off] : 0;
        __syncthreads();
        s[tid] += t;
        __syncthreads();
    }
    int run = s[tid] - S;
#pragma unroll
    for (int q = 0; q < 7; ++q) {
        int k = k0 + q;
        if (k < NBUCK) { bbase[k] = run; run += v[q]; }
    }
}

// ---- placement: bucket-sorted packed records via LDS cursors ----
__global__ __launch_bounds__(256) void k_place(const int* __restrict__ src,
                                               const int* __restrict__ dst,
                                               const int* __restrict__ bbase,
                                               const int* __restrict__ boff,
                                               int* __restrict__ ebuf) {
    __shared__ int cur[NBUCK];
    int tid = threadIdx.x, i = blockIdx.x;
    for (int k = tid; k < NBUCK; k += 256) cur[k] = bbase[k] + boff[i * NBUCK + k];
    __syncthreads();
    int e0 = i * CHUNK;
    for (int e = e0 + tid; e < e0 + CHUNK; e += 256) {
        unsigned d = (unsigned)dst[e];
        if (d >= NN) continue;
        unsigned s = (unsigned)src[e];
        if (s >= NN) s = 0;
        int pos = atomicAdd(&cur[d >> 6], 1);
        ebuf[pos] = (int)(s | ((d & 63u) << 17));
    }
}

// ---- per-bucket: per-node counts -> row_start/dinv, src-only csr ----
__global__ __launch_bounds__(256) void k_binC(const int* __restrict__ bbase,
                                              const int* __restrict__ tot,
                                              const int* __restrict__ ebuf,
                                              int* __restrict__ row_start,
                                              float* __restrict__ dinv,
                                              int* __restrict__ csr) {
    __shared__ int cnt[64], excl[64], cur[64];
    int b = blockIdx.x, tid = threadIdx.x;
    int n0 = b * 64;
    int base = bbase[b], end = base + tot[b];
    if (tid < 64) cnt[tid] = 0;
    __syncthreads();
    for (int i = base + tid; i < end; i += 256)
        atomicAdd(&cnt[((unsigned)ebuf[i]) >> 17], 1);
    __syncthreads();
    if (tid == 0) {
        int run = 0;
        for (int t = 0; t < 64; ++t) { excl[t] = run; run += cnt[t]; }
    }
    __syncthreads();
    if (tid < 64) {
        int node = n0 + tid;
        if (node < NN) {
            row_start[node] = base + excl[tid];
            dinv[node] = rsqrtf((float)cnt[tid] + 1.0f);
        }
        cur[tid] = base + excl[tid];
    }
    if (b == NBUCK - 1 && tid == 0) row_start[NN] = end;
    __syncthreads();
    for (int i = base + tid; i < end; i += 256) {
        unsigned rec = (unsigned)ebuf[i];
        int pos = atomicAdd(&cur[rec >> 17], 1);
        csr[pos] = (int)(rec & 0x1FFFFu);
    }
}

// ---- layer-1 aggregate: P[n] = bf16( xb[n]*sn + sum w_e*xb[src_e] ), MLP=8 ----
__global__ __launch_bounds__(256) void k_agg1(const unsigned short* __restrict__ xb,
                                              const float* __restrict__ dinv,
                                              const int* __restrict__ row_start,
                                              const int* __restrict__ csr,
                                              char* __restrict__ P) {
    int node = blockIdx.x * 4 + (threadIdx.x >> 6);   // grid = NN/4 exactly
    int lane = threadIdx.x & 63;
    float dv = dinv[node]; float sn = dv * dv;
    unsigned int sv = ((const unsigned int*)(xb + (size_t)node * 128))[lane];
    float ax = b2f((unsigned short)(sv & 0xFFFF)) * sn;
    float ay = b2f((unsigned short)(sv >> 16)) * sn;
    int base = row_start[node], end = row_start[node + 1];
    for (int i0 = base; i0 < end; i0 += 64) {
        int idx = i0 + lane;
        int s = (idx < end) ? csr[idx] : 0;
        float wv = (idx < end) ? dinv[s] * dv : 0.f;
        int m = min(64, end - i0);
        int j = 0;
        for (; j + 7 < m; j += 8) {
            int   s0 = __shfl(s, j),     s1 = __shfl(s, j + 1);
            int   s2 = __shfl(s, j + 2), s3 = __shfl(s, j + 3);
            int   s4 = __shfl(s, j + 4), s5 = __shfl(s, j + 5);
            int   s6 = __shfl(s, j + 6), s7 = __shfl(s, j + 7);
            float w0 = __shfl(wv, j),     w1 = __shfl(wv, j + 1);
            float w2 = __shfl(wv, j + 2), w3 = __shfl(wv, j + 3);
            float w4 = __shfl(wv, j + 4), w5 = __shfl(wv, j + 5);
            float w6 = __shfl(wv, j + 6), w7 = __shfl(wv, j + 7);
            unsigned int v0 = ((const unsigned int*)(xb + (size_t)s0 * 128))[lane];
            unsigned int v1 = ((const unsigned int*)(xb + (size_t)s1 * 128))[lane];
            unsigned int v2 = ((const unsigned int*)(xb + (size_t)s2 * 128))[lane];
            unsigned int v3 = ((const unsigned int*)(xb + (size_t)s3 * 128))[lane];
            unsigned int v4 = ((const unsigned int*)(xb + (size_t)s4 * 128))[lane];
            unsigned int v5 = ((const unsigned int*)(xb + (size_t)s5 * 128))[lane];
            unsigned int v6 = ((const unsigned int*)(xb + (size_t)s6 * 128))[lane];
            unsigned int v7 = ((const unsigned int*)(xb + (size_t)s7 * 128))[lane];
            ax = fmaf(b2f((unsigned short)(v0 & 0xFFFF)), w0, ax);
            ay = fmaf(b2f((unsigned short)(v0 >> 16)),    w0, ay);
            ax = fmaf(b2f((unsigned short)(v1 & 0xFFFF)), w1, ax);
            ay = fmaf(b2f((unsigned short)(v1 >> 16)),    w1, ay);
            ax = fmaf(b2f((unsigned short)(v2 & 0xFFFF)), w2, ax);
            ay = fmaf(b2f((unsigned short)(v2 >> 16)),    w2, ay);
            ax = fmaf(b2f((unsigned short)(v3 & 0xFFFF)), w3, ax);
            ay = fmaf(b2f((unsigned short)(v3 >> 16)),    w3, ay);
            ax = fmaf(b2f((unsigned short)(v4 & 0xFFFF)), w4, ax);
            ay = fmaf(b2f((unsigned short)(v4 >> 16)),    w4, ay);
            ax = fmaf(b2f((unsigned short)(v5 & 0xFFFF)), w5, ax);
            ay = fmaf(b2f((unsigned short)(v5 >> 16)),    w5, ay);
            ax = fmaf(b2f((unsigned short)(v6 & 0xFFFF)), w6, ax);
            ay = fmaf(b2f((unsigned short)(v6 >> 16)),    w6, ay);
            ax = fmaf(b2f((unsigned short)(v7 & 0xFFFF)), w7, ax);
            ay = fmaf(b2f((unsigned short)(v7 >> 16)),    w7, ay);
        }
        for (; j < m; ++j) {
            int s0 = __shfl(s, j);
            float w0 = __shfl(wv, j);
            unsigned int v0 = ((const unsigned int*)(xb + (size_t)s0 * 128))[lane];
            ax = fmaf(b2f((unsigned short)(v0 & 0xFFFF)), w0, ax);
            ay = fmaf(b2f((unsigned short)(v0 >> 16)),    w0, ay);
        }
    }
    unsigned int o = (unsigned int)f2b(ax) | ((unsigned int)f2b(ay) << 16);
    ((unsigned int*)(P + (size_t)node * 256))[lane] = o;
}

// ---- fused GEMM1+GEMM2 (MFMA): t2 = bf16( relu(agg@W1+b1) @ W2 ), in-place ----
__global__ __launch_bounds__(256) void k_gemm12(const float* __restrict__ W1,
                                                const float* __restrict__ b1,
                                                const float* __restrict__ W2,
                                                char* __restrict__ P) {
    __shared__ short Wl1[16384];                    // [ct8][ks4][lane64][j8]
    __shared__ short Wl2[8192];                     // [ct4][ks4][lane64][j8]
    __shared__ __align__(16) short Cl[4][16][128];
    const int tid = threadIdx.x;
    const int w = tid >> 6, lane = tid & 63;
    const int r0 = blockIdx.x * 64;

    for (int i = tid; i < 16384; i += 256) {
        int j = i & 7, l = (i >> 3) & 63, ks = (i >> 9) & 3, ct = i >> 11;
        Wl1[i] = (short)f2b(W1[(ks * 32 + ((l >> 4) << 3) + j) * 128 + ct * 16 + (l & 15)]);
    }
    for (int i = tid; i < 8192; i += 256) {
        int j = i & 7, l = (i >> 3) & 63, ks = (i >> 9) & 3, ct = i >> 11;
        Wl2[i] = (short)f2b(W2[(ks * 32 + ((l >> 4) << 3) + j) * 64 + ct * 16 + (l & 15)]);
    }
    __syncthreads();

    const int m = r0 + w * 16 + (lane & 15);
    const int quad = lane >> 4;
    const bool mok = (m < NN);
    bf16x8 a[4];
#pragma unroll
    for (int ks = 0; ks < 4; ++ks) {
        if (mok) a[ks] = *(const bf16x8*)(P + (size_t)m * 256 + (ks * 32 + quad * 8) * 2);
        else     a[ks] = bf16x8{0,0,0,0,0,0,0,0};
    }
#pragma unroll
    for (int ct = 0; ct < 8; ++ct) {
        f32x4 c = {0.f, 0.f, 0.f, 0.f};
#pragma unroll
        for (int ks = 0; ks < 4; ++ks) {
            bf16x8 b = *(const bf16x8*)&Wl1[((ct * 4 + ks) * 64 + lane) * 8];
            c = __builtin_amdgcn_mfma_f32_16x16x32_bf16(a[ks], b, c, 0, 0, 0);
        }
        int col = ct * 16 + (lane & 15);
        float bias = b1[col];
#pragma unroll
        for (int r = 0; r < 4; ++r)
            Cl[w][quad * 4 + r][col] = (short)f2b(fmaxf(c[r] + bias, 0.f));
    }
    __syncthreads();
    bf16x8 a2[4];
#pragma unroll
    for (int ks = 0; ks < 4; ++ks)
        a2[ks] = *(const bf16x8*)&Cl[w][lane & 15][ks * 32 + quad * 8];
    __syncthreads();
    short* Ct = &Cl[0][0][0];   // [64 rows][64 cols]
#pragma unroll
    for (int ct = 0; ct < 4; ++ct) {
        f32x4 c = {0.f, 0.f, 0.f, 0.f};
#pragma unroll
        for (int ks = 0; ks < 4; ++ks) {
            bf16x8 b = *(const bf16x8*)&Wl2[((ct * 4 + ks) * 64 + lane) * 8];
            c = __builtin_amdgcn_mfma_f32_16x16x32_bf16(a2[ks], b, c, 0, 0, 0);
        }
        int col = ct * 16 + (lane & 15);
#pragma unroll
        for (int r = 0; r < 4; ++r)
            Ct[(w * 16 + quad * 4 + r) * 64 + col] = (short)f2b(c[r]);
    }
    __syncthreads();
    for (int it = 0; it < 8; ++it) {
        int row = it * 2 + (lane >> 5), u = lane & 31;
        int node = r0 + w * 16 + row;
        if (node < NN)
            *(unsigned int*)(P + (size_t)node * 256 + u * 4) =
                ((const unsigned int*)&Ct[(w * 16 + row) * 64])[u];
    }
}

// ---- layer-2 aggregate + epilogue, 2 nodes/wave (dword gathers) ----
__global__ __launch_bounds__(256) void k_agg2(const float* __restrict__ dinv,
                                              const int* __restrict__ row_start,
                                              const int* __restrict__ csr,
                                              const char* __restrict__ P,
                                              const float* __restrict__ b2,
                                              float* __restrict__ outp) {
    int lane = threadIdx.x & 63;
    int half = lane >> 5, h = lane & 31;
    int node = blockIdx.x * 8 + (threadIdx.x >> 6) * 2 + half;   // grid = NN/8 exactly
    float dv = dinv[node]; float sn = dv * dv;
    unsigned int tv = *(const unsigned int*)(P + (size_t)node * 256 + h * 4);
    float ax = b2f((unsigned short)(tv & 0xFFFF)) * sn;
    float ay = b2f((unsigned short)(tv >> 16)) * sn;
    int base = row_start[node], end = row_start[node + 1];
    int m_own = end - base;
    int mmax = max(m_own, __shfl(m_own, lane ^ 32));
    int hsel = lane & 32;
    for (int off = 0; off < mmax; off += 32) {
        int idx = base + off + h;
        bool valid = (off + h) < m_own;
        int s = valid ? csr[idx] : 0;
        float wv = valid ? dinv[s] * dv : 0.f;
        int cnt = min(32, mmax - off);
        int j = 0;
        for (; j + 3 < cnt; j += 4) {
            int   s0 = __shfl(s, hsel + j),     s1 = __shfl(s, hsel + j + 1);
            int   s2 = __shfl(s, hsel + j + 2), s3 = __shfl(s, hsel + j + 3);
            float w0 = __shfl(wv, hsel + j),     w1 = __shfl(wv, hsel + j + 1);
            float w2 = __shfl(wv, hsel + j + 2), w3 = __shfl(wv, hsel + j + 3);
            unsigned int v0 = *(const unsigned int*)(P + (size_t)s0 * 256 + h * 4);
            unsigned int v1 = *(const unsigned int*)(P + (size_t)s1 * 256 + h * 4);
            unsigned int v2 = *(const unsigned int*)(P + (size_t)s2 * 256 + h * 4);
            unsigned int v3 = *(const unsigned int*)(P + (size_t)s3 * 256 + h * 4);
            ax = fmaf(b2f((unsigned short)(v0 & 0xFFFF)), w0, ax);
            ay = fmaf(b2f((unsigned short)(v0 >> 16)),    w0, ay);
            ax = fmaf(b2f((unsigned short)(v1 & 0xFFFF)), w1, ax);
            ay = fmaf(b2f((unsigned short)(v1 >> 16)),    w1, ay);
            ax = fmaf(b2f((unsigned short)(v2 & 0xFFFF)), w2, ax);
            ay = fmaf(b2f((unsigned short)(v2 >> 16)),    w2, ay);
            ax = fmaf(b2f((unsigned short)(v3 & 0xFFFF)), w3, ax);
            ay = fmaf(b2f((unsigned short)(v3 >> 16)),    w3, ay);
        }
        for (; j < cnt; ++j) {
            int s0 = __shfl(s, hsel + j);
            float w0 = __shfl(wv, hsel + j);
            unsigned int v0 = *(const unsigned int*)(P + (size_t)s0 * 256 + h * 4);
            ax = fmaf(b2f((unsigned short)(v0 & 0xFFFF)), w0, ax);
            ay = fmaf(b2f((unsigned short)(v0 >> 16)),    w0, ay);
        }
    }
    float2 bb = ((const float2*)b2)[h];
    float2 o; o.x = ax + bb.x; o.y = ay + bb.y;
    ((float2*)(outp + (size_t)node * 64))[h] = o;
}

extern "C" void kernel_launch(void* const* d_in, const int* in_sizes, int n_in,
                              void* d_out, int out_size, void* d_ws, size_t ws_size,
                              hipStream_t stream) {
    const float* x  = (const float*)d_in[0];
    const int*   ei = (const int*)d_in[1];
    const float* W1 = (const float*)d_in[2];
    const float* b1 = (const float*)d_in[3];
    const float* W2 = (const float*)d_in[4];
    const float* b2 = (const float*)d_in[5];
    float* out = (float*)d_out;
    const int* src = ei;
    const int* dst = ei + NE;

    char* ws = (char*)d_ws;
    unsigned short* xb        = (unsigned short*)(ws + 0);
    int*            ghist     = (int*)(ws + 25600000);
    int*            boff      = (int*)(ws + 32000000);
    int*            tot       = (int*)(ws + 38400000);
    int*            bbase     = (int*)(ws + 38440000);
    int*            row_start = (int*)(ws + 38480000);
    float*          dinv      = (float*)(ws + 38900000);
    int*            ebuf      = (int*)(ws + 39300000);
    int*            csr       = (int*)(ws + 45700000);
    char*           P         = ws + 52100000;

    k_pre  <<<NBH + NBXB, 256, 0, stream>>>(x, xb, dst, ghist);
    k_scanB<<<(NBUCK + 255) / 256, 256, 0, stream>>>(ghist, boff, tot);
    k_scanT<<<1, 256, 0, stream>>>(tot, bbase);
    k_place<<<NBH, 256, 0, stream>>>(src, dst, bbase, boff, ebuf);
    k_binC <<<NBUCK, 256, 0, stream>>>(bbase, tot, ebuf, row_start, dinv, csr);

    k_agg1  <<<NN / 4, 256, 0, stream>>>(xb, dinv, row_start, csr, P);
    k_gemm12<<<NBUCK, 256, 0, stream>>>(W1, b1, W2, P);
    k_agg2  <<<NN / 8, 256, 0, stream>>>(dinv, row_start, csr, P, b2, out);
}